// Round 3
// baseline (9042.351 us; speedup 1.0000x reference)
//
#include <hip/hip_runtime.h>

// ---------------- problem constants ----------------
#define HND    233            // hidden size H
#define NL     6              // layers L
#define GPL    30             // workgroups per layer
#define UPW    8              // hidden units per WG (30*8 = 240 >= 233)
#define ROWS   32             // gate rows per WG (4*UPW)
#define TSTEPS 16             // LSTM scan length (= B of reference)
#define FSTEPS 96             // autoregressive steps (= F)
#define NSLOT  (TSTEPS*FSTEPS)
#define CDIM   12             // token dim C
#define G4H    (4*HND)        // 932
#define RL1    468            // layer>0 row length: [x 233 | h 233 | pad 2]
#define RL0    248            // layer0 row length: [tok 12 | h 233 | pad 3]
#define WLP    236            // padded Wl row (233 -> 236)
#define AG __HIP_MEMORY_SCOPE_AGENT
#define SENT 0x7FBADBADu      // NaN bit pattern: real data can never equal this

__device__ __forceinline__ float sigf(float x) { return 1.f / (1.f + expf(-x)); }

// Re-poison hout to sentinel each run (write-once dataflow).
__global__ void init_kernel(unsigned* __restrict__ hout_u) {
  size_t i = (size_t)blockIdx.x * blockDim.x + threadIdx.x;
  size_t stride = (size_t)gridDim.x * blockDim.x;
  const size_t nh = (size_t)NL * NSLOT * HND;
  for (size_t k = i; k < nh; k += stride) hout_u[k] = SENT;
}

// grid: NL*GPL blocks, 64 threads (1 wave) each. Head folded into layer 0.
__global__ void __launch_bounds__(64) lstm_pipe(
    const float* __restrict__ X,
    const float* __restrict__ Wih0, const float* __restrict__ Wih,
    const float* __restrict__ Whh,  const float* __restrict__ bih,
    const float* __restrict__ bhh,  const float* __restrict__ Wl,
    const float* __restrict__ bl,   float* __restrict__ out,
    float* __restrict__ hout) {
  __shared__ float w[ROWS * RL1];      // 59904 B: per-WG weight rows [Wih | Whh | pad]
  __shared__ float vin[RL1];           // [x/tok | hprev | pad]
  __shared__ float hb[WLP];            // layer0: polled h5 for token dot
  __shared__ float wl[CDIM * WLP];     // layer0: Wl rows (padded)
  __shared__ float xs[TSTEPS * CDIM];  // layer0: f=0 seed tokens

  const int ln  = threadIdx.x;         // lane 0..63 (single wave)
  const int bid = blockIdx.x;
  const int l = bid / GPL, g = bid % GPL;
  const int j0 = g * UPW;
  const int U  = min(UPW, HND - j0);   // last WG: 1 unit
  const int Din = (l == 0) ? CDIM : HND;
  const int rl  = (l == 0) ? RL0 : RL1;
  const int rl4 = rl >> 2;
  unsigned* hu = (unsigned*)hout;

  // ---- prologue: weights into LDS. local row r = u*4+gate, global row = gate*H+j0+u
  const float* wih = (l == 0) ? Wih0 : (Wih + (size_t)(l - 1) * G4H * HND);
  const float* whh = Whh + (size_t)l * G4H * HND;
  for (int idx = ln; idx < ROWS * rl; idx += 64) {
    int r = idx / rl, k = idx - r * rl;
    int u = r >> 2, gt = r & 3;
    float v = 0.f;
    if (u < U) {
      int grow = gt * HND + j0 + u;
      if (k < Din) v = wih[(size_t)grow * Din + k];
      else if (k < Din + HND) v = whh[(size_t)grow * HND + (k - Din)];
    }
    w[r * rl + k] = v;
  }
  float biasr = 0.f;
  if (ln < ROWS) {
    int u = ln >> 2, gt = ln & 3;
    if (u < U) {
      int grow = gt * HND + j0 + u;
      biasr = bih[l * G4H + grow] + bhh[l * G4H + grow];
    }
  }
  float blv = 0.f;
  if (l == 0) {
    for (int idx = ln; idx < CDIM * WLP; idx += 64) {
      int c = idx / WLP, k = idx - c * WLP;
      wl[idx] = (k < HND) ? Wl[c * HND + k] : 0.f;
    }
    for (int idx = ln; idx < TSTEPS * CDIM; idx += 64) {
      int t = idx / CDIM, c = idx - t * CDIM;
      xs[idx] = X[((size_t)t * 96 + 95) * CDIM + c];   // X[t][95][c], X is (16,96,12)
    }
    if (ln < CDIM) blv = bl[ln];
  }
  for (int k = ln; k < RL1; k += 64) vin[k] = 0.f;   // zero pads (avoid 0*NaN)
  for (int k = ln; k < WLP; k += 64) hb[k] = 0.f;
  __syncthreads();

  // ---- matvec lane mapping: 2 lanes per row, contiguous k-halves
  const int r = ln & 31, half = ln >> 5;
  const int chalf = (rl4 + 1) >> 1;
  const int c0 = half ? chalf : 0;
  const int c1 = half ? rl4 : chalf;
  const float4* wr4 = (const float4*)(w + r * rl);
  const float4* vi4 = (const float4*)vin;

  float cstate = 0.f;

  for (int s = 0; s < NSLOT; ++s) {
    const int t = s & 15;
    const bool needx = (l > 0) || (s >= TSTEPS);
    const bool needh = (t > 0);
    const unsigned* px = (l == 0)
        ? (hu + ((size_t)5 * NSLOT + (needx ? s - TSTEPS : 0)) * HND)
        : (hu + ((size_t)(l - 1) * NSLOT + s) * HND);
    const unsigned* ph = hu + ((size_t)l * NSLOT + (needh ? s - 1 : 0)) * HND;

    // ---- poll data itself into regs (write-once; SENT => not yet produced)
    unsigned rx[4] = {0, 0, 0, 0}, rh[4] = {0, 0, 0, 0};
    long guard = 0;
    for (;;) {
      bool ok = true;
      #pragma unroll
      for (int q = 0; q < 4; ++q) {
        int i = ln + q * 64;
        if (needx && i < HND) {
          unsigned v = __hip_atomic_load(px + i, __ATOMIC_RELAXED, AG);
          rx[q] = v;
          ok = ok && (v != SENT);
        }
      }
      #pragma unroll
      for (int q = 0; q < 4; ++q) {
        int i = ln + q * 64;
        if (needh && i < HND) {
          unsigned v = __hip_atomic_load(ph + i, __ATOMIC_RELAXED, AG);
          rh[q] = v;
          ok = ok && (v != SENT);
        }
      }
      if (__all(ok)) break;
      __builtin_amdgcn_s_sleep(1);
      if (++guard > (1L << 20)) break;   // safety bail (NaNs propagate loudly)
    }
    // ---- stage into LDS
    #pragma unroll
    for (int q = 0; q < 4; ++q) {
      int i = ln + q * 64;
      if (i < HND) {
        if (l == 0) {
          if (needx) hb[i] = __uint_as_float(rx[q]);
        } else {
          vin[i] = __uint_as_float(rx[q]);
        }
        vin[Din + i] = needh ? __uint_as_float(rh[q]) : 0.f;
      }
    }
    __syncthreads();

    if (l == 0) {
      // ---- token = Wl . h5(s-16) + bl (or f=0 seed), into vin[0..12)
      if (ln < CDIM) {
        float tok;
        if (s < TSTEPS) {
          tok = xs[t * CDIM + ln];
        } else {
          const float4* wr = (const float4*)(wl + ln * WLP);
          const float4* hv = (const float4*)hb;
          float a0 = 0.f, a1 = 0.f;
          int c = 0;
          for (; c + 2 <= WLP / 4; c += 2) {
            float4 x0 = wr[c], y0 = hv[c], x1 = wr[c + 1], y1 = hv[c + 1];
            a0 = fmaf(x0.w, y0.w, fmaf(x0.z, y0.z, fmaf(x0.y, y0.y, fmaf(x0.x, y0.x, a0))));
            a1 = fmaf(x1.w, y1.w, fmaf(x1.z, y1.z, fmaf(x1.y, y1.y, fmaf(x1.x, y1.x, a1))));
          }
          if (c < WLP / 4) {
            float4 x0 = wr[c], y0 = hv[c];
            a0 = fmaf(x0.w, y0.w, fmaf(x0.z, y0.z, fmaf(x0.y, y0.y, fmaf(x0.x, y0.x, a0))));
          }
          tok = a0 + a1 + blv;
          if (g == 0)
            out[((size_t)t * FSTEPS + ((s >> 4) - 1)) * CDIM + ln] = tok;
        }
        vin[ln] = tok;
      }
      __syncthreads();
    }

    // ---- matvec: each lane = (row, k-half); reduce with one shfl_xor
    float a0 = 0.f, a1 = 0.f;
    int c = c0;
    for (; c + 2 <= c1; c += 2) {
      float4 x0 = wr4[c], y0 = vi4[c], x1 = wr4[c + 1], y1 = vi4[c + 1];
      a0 = fmaf(x0.w, y0.w, fmaf(x0.z, y0.z, fmaf(x0.y, y0.y, fmaf(x0.x, y0.x, a0))));
      a1 = fmaf(x1.w, y1.w, fmaf(x1.z, y1.z, fmaf(x1.y, y1.y, fmaf(x1.x, y1.x, a1))));
    }
    if (c < c1) {
      float4 x0 = wr4[c], y0 = vi4[c];
      a0 = fmaf(x0.w, y0.w, fmaf(x0.z, y0.z, fmaf(x0.y, y0.y, fmaf(x0.x, y0.x, a0))));
    }
    float part = a0 + a1;
    float gate = part + __shfl_xor(part, 32) + biasr;   // lanes 0..31 hold gate[row]

    // ---- cell update: lane u < U owns unit j0+u; gates live in lanes 4u..4u+3
    float gi = __shfl(gate, (ln & 7) * 4 + 0);
    float gf = __shfl(gate, (ln & 7) * 4 + 1);
    float gg = __shfl(gate, (ln & 7) * 4 + 2);
    float go = __shfl(gate, (ln & 7) * 4 + 3);
    if (ln < U) {
      float cp = (t == 0) ? 0.f : cstate;
      float cn = sigf(gf) * cp + sigf(gi) * tanhf(gg);
      float hn = sigf(go) * tanhf(cn);
      cstate = cn;
      __hip_atomic_store(hout + ((size_t)l * NSLOT + s) * HND + j0 + ln, hn,
                         __ATOMIC_RELAXED, AG);
    }
    // no fence/flag; next iteration's poll + barrier protect LDS reuse.
  }

  // ---- tail: tokens for f=95 (head slots 1520..1535), computed by (l0,g0) only
  if (l == 0 && g == 0) {
    for (int s = NSLOT; s < NSLOT + TSTEPS; ++s) {
      const unsigned* px = hu + ((size_t)5 * NSLOT + (s - TSTEPS)) * HND;
      unsigned rx[4] = {0, 0, 0, 0};
      long guard = 0;
      for (;;) {
        bool ok = true;
        #pragma unroll
        for (int q = 0; q < 4; ++q) {
          int i = ln + q * 64;
          if (i < HND) {
            unsigned v = __hip_atomic_load(px + i, __ATOMIC_RELAXED, AG);
            rx[q] = v;
            ok = ok && (v != SENT);
          }
        }
        if (__all(ok)) break;
        __builtin_amdgcn_s_sleep(1);
        if (++guard > (1L << 20)) break;
      }
      #pragma unroll
      for (int q = 0; q < 4; ++q) {
        int i = ln + q * 64;
        if (i < HND) hb[i] = __uint_as_float(rx[q]);
      }
      __syncthreads();
      if (ln < CDIM) {
        const float4* wr = (const float4*)(wl + ln * WLP);
        const float4* hv = (const float4*)hb;
        float a0 = 0.f, a1 = 0.f;
        int c = 0;
        for (; c + 2 <= WLP / 4; c += 2) {
          float4 x0 = wr[c], y0 = hv[c], x1 = wr[c + 1], y1 = hv[c + 1];
          a0 = fmaf(x0.w, y0.w, fmaf(x0.z, y0.z, fmaf(x0.y, y0.y, fmaf(x0.x, y0.x, a0))));
          a1 = fmaf(x1.w, y1.w, fmaf(x1.z, y1.z, fmaf(x1.y, y1.y, fmaf(x1.x, y1.x, a1))));
        }
        if (c < WLP / 4) {
          float4 x0 = wr[c], y0 = hv[c];
          a0 = fmaf(x0.w, y0.w, fmaf(x0.z, y0.z, fmaf(x0.y, y0.y, fmaf(x0.x, y0.x, a0))));
        }
        out[((size_t)(s & 15) * FSTEPS + 95) * CDIM + ln] = a0 + a1 + blv;
      }
      __syncthreads();   // protect hb reuse across tail iterations
    }
  }
}

extern "C" void kernel_launch(void* const* d_in, const int* in_sizes, int n_in,
                              void* d_out, int out_size, void* d_ws, size_t ws_size,
                              hipStream_t stream) {
  const float* X    = (const float*)d_in[0];
  const float* Wih0 = (const float*)d_in[1];
  const float* Wih  = (const float*)d_in[2];
  const float* Whh  = (const float*)d_in[3];
  const float* bih  = (const float*)d_in[4];
  const float* bhh  = (const float*)d_in[5];
  const float* Wl   = (const float*)d_in[6];
  const float* bl   = (const float*)d_in[7];

  // workspace: hout[6][1536][233] f32 ~= 8.59 MB
  float* hout = (float*)d_ws;

  init_kernel<<<2048, 256, 0, stream>>>((unsigned*)hout);
  lstm_pipe<<<NL * GPL, 64, 0, stream>>>(X, Wih0, Wih, Whh, bih, bhh, Wl, bl,
                                         (float*)d_out, hout);
}

// Round 4
// 4962.217 us; speedup vs baseline: 1.8222x; 1.8222x over previous
//
#include <hip/hip_runtime.h>

// ---------------- problem constants ----------------
#define HND    233            // hidden size H
#define NL     6              // layers L
#define GPL    30             // workgroups per layer
#define UPW    8              // hidden units per WG
#define ROWS   32             // gate rows per WG (4*UPW)
#define TSTEPS 16             // LSTM scan length (= B of reference)
#define FSTEPS 96             // autoregressive steps (= F)
#define NSLOT  (TSTEPS*FSTEPS)
#define CDIM   12             // token dim C
#define G4H    (4*HND)        // 932
#define RLMAX  484            // l>0 LDS row stride: [x 240 | h 240 | pad 4]  (484%32=4)
#define RL0    260            // l0  LDS row stride: [tok 16 | h 240 | pad 4] (260%32=4)
#define XW1    240            // x-section width, l>0
#define XW0    16             // x-section width, l0
#define BLOCK  128
#define AG __HIP_MEMORY_SCOPE_AGENT
#define SENT 0x7FBADBADu      // NaN bit pattern: real data can never equal this

__device__ __forceinline__ float sigf(float x) { return 1.f / (1.f + expf(-x)); }

// Re-poison hout (data words -> SENT, pad words -> 0) and xin (seed f=0 tokens).
__global__ void init_kernel(const float* __restrict__ X,
                            unsigned* __restrict__ hout,
                            unsigned* __restrict__ xin, int hp) {
  size_t i = (size_t)blockIdx.x * blockDim.x + threadIdx.x;
  size_t stride = (size_t)gridDim.x * blockDim.x;
  const size_t nh = (size_t)NL * NSLOT * hp;
  for (size_t k = i; k < nh; k += stride) {
    int d = (int)(k % hp);
    hout[k] = (d < HND) ? SENT : 0u;
  }
  for (size_t k = i; k < (size_t)NSLOT * CDIM; k += stride) {
    int s = (int)(k / CDIM), c = (int)(k % CDIM);
    if (s < TSTEPS) ((float*)xin)[k] = X[((size_t)s * 96 + 95) * CDIM + c];
    else xin[k] = SENT;
  }
}

// grid: 240 blocks x 128 threads. role: l = bid%8 (0..5 layer, 6&g==0 head), g = bid/8.
// With round-robin block->XCD mapping, each layer's 30 WGs share one XCD's L2.
__global__ void __launch_bounds__(BLOCK) lstm_pipe(
    const float* __restrict__ Wih0, const float* __restrict__ Wih,
    const float* __restrict__ Whh,  const float* __restrict__ bih,
    const float* __restrict__ bhh,  const float* __restrict__ Wl,
    const float* __restrict__ bl,   float* __restrict__ out,
    float* __restrict__ hout, float* __restrict__ xin, int hp) {
  __shared__ float w[ROWS * RLMAX];   // 61952 B (head reuses for Wl)
  __shared__ float vin[RLMAX];        // [x | hprev | pad]
  __shared__ float bias[ROWS];
  __shared__ float part[BLOCK];

  const int tid = threadIdx.x;
  const int l = blockIdx.x & 7, g = blockIdx.x >> 3;
  unsigned long long* hu64 = (unsigned long long*)hout;
  const int hp2 = hp >> 1;

  if (l == 7 || (l == 6 && g > 0) || g >= GPL) return;

  if (l == 6) {
    // ---------------- head: token(s+16) = Wl . h5(s) + bl ----------------
    for (int i = tid; i < CDIM * XW1; i += BLOCK) {
      int r = i / XW1, k = i - r * XW1;
      w[i] = (k < HND) ? Wl[r * HND + k] : 0.f;
    }
    const float blv = (tid < CDIM) ? bl[tid] : 0.f;
    for (int k = tid; k < RLMAX; k += BLOCK) vin[k] = 0.f;
    __syncthreads();
    for (int s = 0; s < NSLOT; ++s) {
      const unsigned long long* src = hu64 + ((size_t)5 * NSLOT + s) * hp2;
      unsigned long long vb = 0; long guard = 0;
      for (;;) {
        bool ok = true;
        if (tid < hp2) {
          vb = __hip_atomic_load(src + tid, __ATOMIC_RELAXED, AG);
          ok = ((unsigned)vb != SENT) && ((unsigned)(vb >> 32) != SENT);
        }
        if (__syncthreads_and(ok)) break;
        __builtin_amdgcn_s_sleep(1);
        if (++guard > (1L << 20)) break;
      }
      if (tid < hp2) *(unsigned long long*)(vin + 2 * tid) = vb;
      __syncthreads();
      if (tid < CDIM) {
        const float4* wr = (const float4*)(w + tid * XW1);
        const float4* hv = (const float4*)vin;
        float a0 = 0.f, a1 = 0.f;
        for (int c = 0; c < XW1 / 4; c += 2) {
          float4 x0 = wr[c], y0 = hv[c], x1 = wr[c + 1], y1 = hv[c + 1];
          a0 = fmaf(x0.w, y0.w, fmaf(x0.z, y0.z, fmaf(x0.y, y0.y, fmaf(x0.x, y0.x, a0))));
          a1 = fmaf(x1.w, y1.w, fmaf(x1.z, y1.z, fmaf(x1.y, y1.y, fmaf(x1.x, y1.x, a1))));
        }
        float v = a0 + a1 + blv;
        int t = s & 15, f = s >> 4;
        out[((size_t)t * FSTEPS + f) * CDIM + tid] = v;
        if (s + TSTEPS < NSLOT)
          __hip_atomic_store(xin + (size_t)(s + TSTEPS) * CDIM + tid, v,
                             __ATOMIC_RELAXED, AG);
      }
      // next slot's poll barrier protects vin reuse
    }
    return;
  }

  // ---------------- layer workgroup ----------------
  const int j0 = g * UPW;
  const int U = min(UPW, HND - j0);
  const int XW = (l == 0) ? XW0 : XW1;          // vin x-section width
  const int DinR = (l == 0) ? CDIM : HND;       // real input width
  const int RL = (l == 0) ? RL0 : RLMAX;
  const int RL4 = RL >> 2, KC4 = (RL4 + 3) >> 2;

  const float* wih = (l == 0) ? Wih0 : (Wih + (size_t)(l - 1) * G4H * HND);
  const float* whh = Whh + (size_t)l * G4H * HND;
  for (int idx = tid; idx < ROWS * RL; idx += BLOCK) {
    int r = idx / RL, k = idx - r * RL;
    int u = r >> 2, gt = r & 3;
    float v = 0.f;
    if (u < U) {
      int grow = gt * HND + j0 + u;
      if (k < DinR) v = wih[(size_t)grow * DinR + k];
      else if (k >= XW && k < XW + HND) v = whh[(size_t)grow * HND + (k - XW)];
    }
    w[r * RL + k] = v;
  }
  if (tid < ROWS) {
    int u = tid >> 2, gt = tid & 3;
    bias[tid] = 0.f;
    if (u < U) {
      int grow = gt * HND + j0 + u;
      bias[tid] = bih[l * G4H + grow] + bhh[l * G4H + grow];
    }
  }
  for (int k = tid; k < RLMAX; k += BLOCK) vin[k] = 0.f;
  __syncthreads();

  // matvec mapping: r = row, q = k-quarter
  const int r = tid & 31, q = tid >> 5;
  const int c0 = min(q * KC4, RL4), c1 = min(c0 + KC4, RL4);
  const float4* wr4 = (const float4*)(w + r * RL);
  const float4* vi4 = (const float4*)vin;
  const unsigned long long* xin64 = (const unsigned long long*)xin;

  float cst = 0.f;

  for (int s = 0; s < NSLOT; ++s) {
    const int t = s & 15;
    const bool needh = (t > 0);
    const int nx = (l == 0) ? (CDIM / 2) : hp2;
    const unsigned long long* px = (l == 0)
        ? (xin64 + (size_t)s * (CDIM / 2))
        : (hu64 + ((size_t)(l - 1) * NSLOT + s) * hp2);
    const unsigned long long* ph = hu64 + ((size_t)l * NSLOT + (needh ? s - 1 : 0)) * hp2;

    // ---- poll the data itself, u64 granularity (write-once; SENT => not ready)
    unsigned long long vx = 0, vh = 0;
    long guard = 0;
    for (;;) {
      bool ok = true;
      if (tid < nx) {
        vx = __hip_atomic_load(px + tid, __ATOMIC_RELAXED, AG);
        ok = ((unsigned)vx != SENT) && ((unsigned)(vx >> 32) != SENT);
      }
      if (needh && tid < hp2) {
        vh = __hip_atomic_load(ph + tid, __ATOMIC_RELAXED, AG);
        ok = ok && ((unsigned)vh != SENT) && ((unsigned)(vh >> 32) != SENT);
      }
      if (__syncthreads_and(ok)) break;
      __builtin_amdgcn_s_sleep(1);
      if (++guard > (1L << 20)) break;   // safety bail (NaNs propagate loudly)
    }
    // ---- stage into LDS (8B writes; pads beyond hp stay zero from prologue)
    if (tid < nx) *(unsigned long long*)(vin + 2 * tid) = vx;
    if (tid < hp2) *(unsigned long long*)(vin + XW + 2 * tid) = needh ? vh : 0ull;
    __syncthreads();

    // ---- fused matvec over [x | h] padded row
    float a0 = 0.f, a1 = 0.f;
    int c = c0;
    for (; c + 2 <= c1; c += 2) {
      float4 x0 = wr4[c], y0 = vi4[c], x1 = wr4[c + 1], y1 = vi4[c + 1];
      a0 = fmaf(x0.w, y0.w, fmaf(x0.z, y0.z, fmaf(x0.y, y0.y, fmaf(x0.x, y0.x, a0))));
      a1 = fmaf(x1.w, y1.w, fmaf(x1.z, y1.z, fmaf(x1.y, y1.y, fmaf(x1.x, y1.x, a1))));
    }
    if (c < c1) {
      float4 x0 = wr4[c], y0 = vi4[c];
      a0 = fmaf(x0.w, y0.w, fmaf(x0.z, y0.z, fmaf(x0.y, y0.y, fmaf(x0.x, y0.x, a0))));
    }
    part[tid] = a0 + a1;   // row r, quarter q at part[r + 32q]
    __syncthreads();

    // ---- cell update: thread u<U owns unit j0+u, rows 4u..4u+3
    if (tid < U) {
      float gg[4];
      #pragma unroll
      for (int gt = 0; gt < 4; ++gt) {
        int rr = tid * 4 + gt;
        gg[gt] = part[rr] + part[rr + 32] + part[rr + 64] + part[rr + 96] + bias[rr];
      }
      float cp = needh ? cst : 0.f;
      float cn = sigf(gg[1]) * cp + sigf(gg[0]) * tanhf(gg[2]);
      float hn = sigf(gg[3]) * tanhf(cn);
      cst = cn;
      __hip_atomic_store(hout + ((size_t)l * NSLOT + s) * hp + j0 + tid, hn,
                         __ATOMIC_RELAXED, AG);
    }
    // no fence/flag: consumers poll the data words themselves.
  }
}

extern "C" void kernel_launch(void* const* d_in, const int* in_sizes, int n_in,
                              void* d_out, int out_size, void* d_ws, size_t ws_size,
                              hipStream_t stream) {
  const float* X    = (const float*)d_in[0];
  const float* Wih0 = (const float*)d_in[1];
  const float* Wih  = (const float*)d_in[2];
  const float* Whh  = (const float*)d_in[3];
  const float* bih  = (const float*)d_in[4];
  const float* bhh  = (const float*)d_in[5];
  const float* Wl   = (const float*)d_in[6];
  const float* bl   = (const float*)d_in[7];

  // hout stride: 240 dwords if workspace allows, else 234 (both u64-aligned)
  size_t need240 = ((size_t)NL * NSLOT * 240 + (size_t)NSLOT * CDIM) * 4;
  int hp = (ws_size >= need240) ? 240 : 234;

  float* hout = (float*)d_ws;
  float* xin  = hout + (size_t)NL * NSLOT * hp;

  init_kernel<<<2048, 256, 0, stream>>>(X, (unsigned*)hout, (unsigned*)xin, hp);
  lstm_pipe<<<240, BLOCK, 0, stream>>>(Wih0, Wih, Whh, bih, bhh, Wl, bl,
                                       (float*)d_out, hout, xin, hp);
}

// Round 5
// 4191.438 us; speedup vs baseline: 2.1573x; 1.1839x over previous
//
#include <hip/hip_runtime.h>

// ---------------- problem constants ----------------
#define HND    233            // hidden size H
#define NL     6              // layers L
#define GPL    15             // workgroups per layer
#define UPW    16             // hidden units per WG (15*16 = 240 >= 233)
#define ROWS   64             // gate rows per WG (4*UPW)
#define TSTEPS 16             // LSTM scan length (= B of reference)
#define FSTEPS 96             // autoregressive steps (= F)
#define NSLOT  (TSTEPS*FSTEPS)
#define CDIM   12             // token dim C
#define G4H    (4*HND)        // 932
#define XW1    240            // x-section width, l>0
#define XW0    16             // x-section width, l0
#define RL1    484            // l>0 row stride: [x 240 | h 240 | pad 4]
#define RL0    260            // l0  row stride: [tok 16 | h 240 | pad 4]
#define NU64   117            // u64 words covering one 233-vector (+1 pad dword)
#define BLOCK  256
#define AG __HIP_MEMORY_SCOPE_AGENT
#define SENT 0x7FBADBADu      // NaN bit pattern: real data can never equal this

// dynamic smem layout (floats)
#define OFF_W    0
#define OFF_VIN  (ROWS*RL1)            // 30976
#define OFF_BIAS (OFF_VIN + 2*RL1)     // double-buffered vin
#define OFF_PART (OFF_BIAS + ROWS)
#define OFF_TK   (OFF_PART + BLOCK)
#define OFF_XS   (OFF_TK + 16)
#define SMEM_FLOATS (OFF_XS + TSTEPS*CDIM)   // 32472 floats = 129888 B

__device__ __forceinline__ float sigf(float x) { return 1.f / (1.f + expf(-x)); }

// Per-thread spin on ONE u64 until neither half is the sentinel.
__device__ __forceinline__ unsigned long long spin64(const unsigned long long* p) {
  unsigned long long v; long g = 0;
  for (;;) {
    v = __hip_atomic_load(p, __ATOMIC_RELAXED, AG);
    if ((unsigned)v != SENT && (unsigned)(v >> 32) != SENT) return v;
    if (++g > (1L << 18)) return v;            // safety bail (NaNs fail loudly)
    if (g > 2) __builtin_amdgcn_s_sleep(1);
  }
}

// Re-poison hout (data->SENT, pads->0) and xin (seed f=0 tokens, rest SENT).
__global__ void init_kernel(const float* __restrict__ X,
                            unsigned* __restrict__ hout,
                            unsigned* __restrict__ xin, int hp) {
  size_t i = (size_t)blockIdx.x * blockDim.x + threadIdx.x;
  size_t stride = (size_t)gridDim.x * blockDim.x;
  const size_t nh = (size_t)NL * NSLOT * hp;
  for (size_t k = i; k < nh; k += stride) {
    int d = (int)(k % hp);
    hout[k] = (d < HND) ? SENT : 0u;
  }
  for (size_t k = i; k < (size_t)NSLOT * CDIM; k += stride) {
    int s = (int)(k / CDIM), c = (int)(k % CDIM);
    if (s < TSTEPS) ((float*)xin)[k] = X[((size_t)s * 96 + 95) * CDIM + c];
    else xin[k] = SENT;
  }
}

// grid: NL*GPL + 1 blocks x 256 threads; last block = head (off critical path).
__global__ void __launch_bounds__(BLOCK) lstm_pipe(
    const float* __restrict__ X,
    const float* __restrict__ Wih0, const float* __restrict__ Wih,
    const float* __restrict__ Whh,  const float* __restrict__ bih,
    const float* __restrict__ bhh,  const float* __restrict__ Wl,
    const float* __restrict__ bl,   float* __restrict__ out,
    float* __restrict__ hout, float* __restrict__ xin, int hp) {
  extern __shared__ float sm[];
  float* w    = sm + OFF_W;
  float* vin  = sm + OFF_VIN;    // 2 x RL1 double buffer
  float* bias = sm + OFF_BIAS;
  float* part = sm + OFF_PART;
  float* tk   = sm + OFF_TK;
  float* xs   = sm + OFF_XS;

  const int tid = threadIdx.x;
  const int bid = blockIdx.x;
  unsigned long long* hu64 = (unsigned long long*)hout;
  const int hp2 = hp >> 1;

  if (bid == NL * GPL) {
    // ---------------- head: token(s+16) = Wl . h5(s) + bl ----------------
    for (int i = tid; i < CDIM * XW1; i += BLOCK) {
      int r = i / XW1, k = i - r * XW1;
      w[i] = (k < HND) ? Wl[r * HND + k] : 0.f;
    }
    for (int k = tid; k < 2 * RL1; k += BLOCK) vin[k] = 0.f;
    float blr = (tid < 48) ? bl[tid >> 2] : 0.f;
    __syncthreads();
    for (int s = 0; s < NSLOT; ++s) {
      float* vb = vin + (s & 1) * RL1;
      if (tid < NU64) {
        unsigned long long vh = spin64(hu64 + ((size_t)5 * NSLOT + s) * hp2 + tid);
        *(unsigned long long*)(vb + 2 * tid) = vh;
      }
      __syncthreads();
      if (tid < 48) {                 // 12 rows x 4 k-quarters, all in wave 0
        int r = tid >> 2, q = tid & 3;
        const float4* wr = (const float4*)(w + r * XW1);
        const float4* hv = (const float4*)vb;
        float a = 0.f;
        for (int c = q * 15; c < q * 15 + 15; ++c) {
          float4 x0 = wr[c], y0 = hv[c];
          a = fmaf(x0.w, y0.w, fmaf(x0.z, y0.z, fmaf(x0.y, y0.y, fmaf(x0.x, y0.x, a))));
        }
        a += __shfl_xor(a, 1);
        a += __shfl_xor(a, 2);
        if (q == 0) tk[r] = a + blr;
      }
      __syncthreads();
      int t = s & 15, f = s >> 4;
      if (tid < CDIM) out[((size_t)t * FSTEPS + f) * CDIM + tid] = tk[tid];
      if (s + TSTEPS < NSLOT && tid < 6) {
        unsigned long long pv =
            ((unsigned long long)__float_as_uint(tk[2 * tid + 1]) << 32) |
            (unsigned long long)__float_as_uint(tk[2 * tid]);
        __hip_atomic_store((unsigned long long*)xin + (size_t)(s + TSTEPS) * 6 + tid,
                           pv, __ATOMIC_RELAXED, AG);
      }
      // tk reuse protected by next slot's first barrier
    }
    return;
  }

  // ---------------- layer workgroup ----------------
  const int l = bid / GPL, g = bid % GPL;
  const int j0 = g * UPW;
  const int U = min(UPW, HND - j0);            // last WG: 9 units
  const int XW = (l == 0) ? XW0 : XW1;
  const int DinR = (l == 0) ? CDIM : HND;
  const int RL = (l == 0) ? RL0 : RL1;
  const int RL4 = RL >> 2, KC4 = (RL4 + 3) >> 2;

  const float* wih = (l == 0) ? Wih0 : (Wih + (size_t)(l - 1) * G4H * HND);
  const float* whh = Whh + (size_t)l * G4H * HND;
  for (int idx = tid; idx < ROWS * RL; idx += BLOCK) {
    int r = idx / RL, k = idx - r * RL;
    int u = r >> 2, gt = r & 3;
    float v = 0.f;
    if (u < U) {
      int grow = gt * HND + j0 + u;
      if (k < DinR) v = wih[(size_t)grow * DinR + k];
      else if (k >= XW && k < XW + HND) v = whh[(size_t)grow * HND + (k - XW)];
    }
    w[r * RL + k] = v;
  }
  if (tid < ROWS) {
    int u = tid >> 2, gt = tid & 3;
    bias[tid] = 0.f;
    if (u < U) {
      int grow = gt * HND + j0 + u;
      bias[tid] = bih[l * G4H + grow] + bhh[l * G4H + grow];
    }
  }
  for (int k = tid; k < 2 * RL1; k += BLOCK) vin[k] = 0.f;
  if (l == 0)
    for (int idx = tid; idx < TSTEPS * CDIM; idx += BLOCK)
      xs[idx] = X[((size_t)(idx / CDIM) * 96 + 95) * CDIM + (idx % CDIM)];
  __syncthreads();

  // matvec mapping: r = row (0..63), q = k-quarter (0..3)
  const int r = tid & 63, q = tid >> 6;
  const int c0 = min(q * KC4, RL4), c1 = min(c0 + KC4, RL4);
  const float4* wr4 = (const float4*)(w + r * RL);
  const unsigned long long* xin64 = (const unsigned long long*)xin;

  float cst = 0.f;

  for (int s = 0; s < NSLOT; ++s) {
    const int t = s & 15;
    const bool needh = (t > 0);
    float* vb = vin + (s & 1) * RL1;

    // ---- per-thread independent spin (<=1 u64 per thread)
    unsigned long long vx = 0, vh = 0;
    if (l == 0) {
      if (s >= TSTEPS && tid < 6) vx = spin64(xin64 + (size_t)s * 6 + tid);
    } else {
      if (tid < NU64) vx = spin64(hu64 + ((size_t)(l - 1) * NSLOT + s) * hp2 + tid);
    }
    if (needh && tid >= 128 && tid < 128 + NU64)
      vh = spin64(hu64 + ((size_t)l * NSLOT + s - 1) * hp2 + (tid - 128));

    // ---- stage into the s&1 buffer (prev slot's readers use the other one)
    if (l == 0) {
      if (s < TSTEPS) { if (tid < CDIM) vb[tid] = xs[t * CDIM + tid]; }
      else if (tid < 6) *(unsigned long long*)(vb + 2 * tid) = vx;
    } else {
      if (tid < NU64) *(unsigned long long*)(vb + 2 * tid) = vx;
    }
    if (tid >= 128 && tid < 128 + NU64)
      *(unsigned long long*)(vb + XW + 2 * (tid - 128)) = needh ? vh : 0ull;
    __syncthreads();

    // ---- fused matvec over [x | h] padded row
    const float4* vi4 = (const float4*)vb;
    float a0 = 0.f, a1 = 0.f;
    int c = c0;
    for (; c + 2 <= c1; c += 2) {
      float4 x0 = wr4[c], y0 = vi4[c], x1 = wr4[c + 1], y1 = vi4[c + 1];
      a0 = fmaf(x0.w, y0.w, fmaf(x0.z, y0.z, fmaf(x0.y, y0.y, fmaf(x0.x, y0.x, a0))));
      a1 = fmaf(x1.w, y1.w, fmaf(x1.z, y1.z, fmaf(x1.y, y1.y, fmaf(x1.x, y1.x, a1))));
    }
    if (c < c1) {
      float4 x0 = wr4[c], y0 = vi4[c];
      a0 = fmaf(x0.w, y0.w, fmaf(x0.z, y0.z, fmaf(x0.y, y0.y, fmaf(x0.x, y0.x, a0))));
    }
    part[tid] = a0 + a1;               // row r, quarter q at part[r + 64q]
    __syncthreads();

    // ---- cell update + packed u64 publish (wave 0)
    if (tid < 64) {
      float hn = 0.f;
      if (tid < UPW) {
        float gg[4];
        #pragma unroll
        for (int gt = 0; gt < 4; ++gt) {
          int rr = tid * 4 + gt;
          gg[gt] = part[rr] + part[rr + 64] + part[rr + 128] + part[rr + 192] + bias[rr];
        }
        float cp = needh ? cst : 0.f;
        float cn = sigf(gg[1]) * cp + sigf(gg[0]) * tanhf(gg[2]);
        hn = sigf(gg[3]) * tanhf(cn);
        cst = cn;
      }
      float lo = __shfl(hn, 2 * (tid & 7));
      float hi = __shfl(hn, 2 * (tid & 7) + 1);
      if (tid < ((U + 1) >> 1)) {
        if (2 * tid + 1 >= U) hi = 0.f;
        unsigned long long pv = ((unsigned long long)__float_as_uint(hi) << 32)
                              | (unsigned long long)__float_as_uint(lo);
        __hip_atomic_store(hu64 + (((size_t)l * NSLOT + s) * hp + j0) / 2 + tid,
                           pv, __ATOMIC_RELAXED, AG);
      }
    }
    // no fence/flag: consumers spin on the data words themselves.
  }
}

extern "C" void kernel_launch(void* const* d_in, const int* in_sizes, int n_in,
                              void* d_out, int out_size, void* d_ws, size_t ws_size,
                              hipStream_t stream) {
  const float* X    = (const float*)d_in[0];
  const float* Wih0 = (const float*)d_in[1];
  const float* Wih  = (const float*)d_in[2];
  const float* Whh  = (const float*)d_in[3];
  const float* bih  = (const float*)d_in[4];
  const float* bhh  = (const float*)d_in[5];
  const float* Wl   = (const float*)d_in[6];
  const float* bl   = (const float*)d_in[7];

  size_t need240 = ((size_t)NL * NSLOT * 240 + (size_t)NSLOT * CDIM) * 4;
  int hp = (ws_size >= need240) ? 240 : 234;

  float* hout = (float*)d_ws;
  float* xin  = hout + (size_t)NL * NSLOT * hp;

  hipFuncSetAttribute(reinterpret_cast<const void*>(lstm_pipe),
                      hipFuncAttributeMaxDynamicSharedMemorySize, SMEM_FLOATS * 4);
  init_kernel<<<2048, 256, 0, stream>>>(X, (unsigned*)hout, (unsigned*)xin, hp);
  lstm_pipe<<<NL * GPL + 1, BLOCK, SMEM_FLOATS * 4, stream>>>(
      X, Wih0, Wih, Whh, bih, bhh, Wl, bl, (float*)d_out, hout, xin, hp);
}

// Round 6
// 2236.244 us; speedup vs baseline: 4.0435x; 1.8743x over previous
//
#include <hip/hip_runtime.h>

// ---------------- problem constants ----------------
#define HND    233
#define NL     6
#define GPL    15             // WGs per layer
#define UPW    16             // units per WG (15*16 = 240 >= 233)
#define ROWS   64             // gate rows per WG
#define TSTEPS 16
#define FSTEPS 96
#define NSLOT  (TSTEPS*FSTEPS)
#define CDIM   12
#define G4H    (4*HND)        // 932
#define HP     240            // preferred hout row stride (floats)
#define VINW   496            // vin stream buffer: [x 240 | h 240 | pad 16]
#define NTICK  (6*95+15+1)    // 586 wavefront ticks
#define NHEAD  3
#define BLOCK  256
#define NWORD  234            // u64 words per stream (117 x + 117 h)
#define AG     __HIP_MEMORY_SCOPE_AGENT
#define SENT   0x7FBADBADu    // NaN pattern: unreachable by real data

typedef unsigned long long u64;

__device__ __forceinline__ float sigf(float x) { return 1.f / (1.f + expf(-x)); }
__device__ __forceinline__ bool rdy(u64 v) {
  return ((unsigned)v != SENT) && ((unsigned)(v >> 32) != SENT);
}

// Re-poison hout: data dwords -> SENT, pad dwords -> 0.
__global__ void init_kernel(unsigned* __restrict__ hout, int hp) {
  size_t i = (size_t)blockIdx.x * blockDim.x + threadIdx.x;
  size_t stride = (size_t)gridDim.x * blockDim.x;
  const size_t nh = (size_t)NL * NSLOT * hp;
  for (size_t k = i; k < nh; k += stride) hout[k] = ((int)(k % hp) < HND) ? SENT : 0u;
}

// grid: NL*GPL layer WGs + NHEAD head WGs, 256 threads each.
// Wavefront schedule: layer l processes slot (f,t) at tick d = 6f+t (its own
// loop order); <=3 concurrent f-streams per tick. All inputs for tick d were
// published at tick d-1 (x: layer l-1 same slot, or h5(f-1,t) for l0-folded;
// h: own layer slot-1). Weights live in VGPRs; Wl is folded into layer 0.
__global__ void __launch_bounds__(BLOCK, 1) lstm_pipe(
    const float* __restrict__ X,
    const float* __restrict__ Wih0, const float* __restrict__ Wih,
    const float* __restrict__ Whh,  const float* __restrict__ bih,
    const float* __restrict__ bhh,  const float* __restrict__ Wl,
    const float* __restrict__ bl,   float* __restrict__ out,
    float* __restrict__ hout, int hps /* u64 words per h-row */) {
  __shared__ float vin[3][VINW];        // per-stream [x|h|pad], k-indexed
  __shared__ float part[3][BLOCK];
  __shared__ float bias[ROWS];
  __shared__ float cst[3][UPW];         // c-state, keyed by f%3
  __shared__ float wih0s[ROWS][CDIM];   // l0: raw Wih0 rows (f==0 correction)
  __shared__ float xs[TSTEPS][CDIM];    // l0: f==0 seed  = X[t][95][:]
  __shared__ float wlh[CDIM][HP];       // Wl padded (l0 fold + head dot)

  const int tid = threadIdx.x;
  const int bid = blockIdx.x;
  u64* hu = (u64*)hout;

  if (bid >= NL * GPL) {
    // ---------------- head WGs: out[t][f][:] = Wl.h5(f,t)+bl, f%3==hid ----
    const int hid = bid - NL * GPL;
    for (int i = tid; i < CDIM * HP; i += BLOCK) {
      int rr = i / HP, k = i % HP;
      ((float*)wlh)[i] = (k < HND) ? Wl[rr * HND + k] : 0.f;
    }
    for (int i = tid; i < VINW; i += BLOCK) vin[0][i] = 0.f;
    __syncthreads();
    for (int f = hid; f < FSTEPS; f += NHEAD) {
      for (int t = 0; t < TSTEPS; ++t) {
        const u64* src = hu + ((size_t)5 * NSLOT + 16 * f + t) * hps;
        if (tid < 117) {
          u64 v; long gd = 0;
          for (;;) {
            v = __hip_atomic_load(src + tid, __ATOMIC_RELAXED, AG);
            if (rdy(v)) break;
            if (++gd > (1L << 20)) break;
            if (gd > 4) __builtin_amdgcn_s_sleep(1);
          }
          *(u64*)&vin[0][2 * tid] = v;
        }
        __syncthreads();
        if (tid < 48) {
          int rr = tid >> 2, q = tid & 3;
          const float4* wr = (const float4*)&wlh[rr][0];
          const float4* hv = (const float4*)&vin[0][0];
          float a = 0.f;
          #pragma unroll
          for (int c = 0; c < 15; ++c) {
            float4 x0 = wr[q * 15 + c], y0 = hv[q * 15 + c];
            a = fmaf(x0.w, y0.w, fmaf(x0.z, y0.z, fmaf(x0.y, y0.y, fmaf(x0.x, y0.x, a))));
          }
          a += __shfl_xor(a, 1);
          a += __shfl_xor(a, 2);
          if (q == 0) out[((size_t)t * FSTEPS + f) * CDIM + rr] = a + bl[rr];
        }
        __syncthreads();
      }
    }
    return;
  }

  // ---------------- layer workgroup ----------------
  const int l = bid / GPL, g = bid % GPL;
  const int j0 = g * UPW;
  const int U = min(UPW, HND - j0);            // last WG: 9 units
  const int r = tid & 63, q = tid >> 6;        // matvec row / k-quarter
  const int u = r >> 2, gt = r & 3;
  const int grow = gt * HND + j0 + u;
  const bool rowok = (u < U);

  // ---- small LDS tables
  if (l == 0) {
    for (int i = tid; i < CDIM * HP; i += BLOCK) {
      int rr = i / HP, k = i % HP;
      ((float*)wlh)[i] = (k < HND) ? Wl[rr * HND + k] : 0.f;
    }
    for (int i = tid; i < ROWS * CDIM; i += BLOCK) {
      int rr = i / CDIM, c = i % CDIM;
      int uu = rr >> 2, g2 = rr & 3;
      wih0s[rr][c] = (uu < U) ? Wih0[(g2 * HND + j0 + uu) * CDIM + c] : 0.f;
    }
    for (int i = tid; i < TSTEPS * CDIM; i += BLOCK)
      xs[i / CDIM][i % CDIM] = X[((size_t)(i / CDIM) * 96 + 95) * CDIM + (i % CDIM)];
  }
  for (int i = tid; i < 3 * VINW; i += BLOCK) ((float*)vin)[i] = 0.f;
  __syncthreads();

  // ---- weights into REGISTERS (121-float slice; statically indexed)
  // row layout: [x-weights 240 | Whh 240 | pad 16]; l0 x-weights = Wih0 @ Wl.
  float4 w4[31];
  const float* wihl = Wih + (size_t)(l - 1) * G4H * HND;
  const float* whhl = Whh + (size_t)l * G4H * HND;
  #pragma unroll
  for (int j = 0; j < 31; ++j) {
    float e[4];
    #pragma unroll
    for (int ee = 0; ee < 4; ++ee) {
      const int idx = (q * 31 + j) * 4 + ee;
      float v = 0.f;
      if (rowok) {
        if (idx < HND) {
          if (l == 0) {
            float acc = 0.f;
            #pragma unroll
            for (int c = 0; c < CDIM; ++c) acc = fmaf(wih0s[r][c], wlh[c][idx], acc);
            v = acc;
          } else {
            v = wihl[(size_t)grow * HND + idx];
          }
        } else if (idx >= HP && idx < HP + HND) {
          v = whhl[(size_t)grow * HND + (idx - HP)];
        }
      }
      e[ee] = v;
    }
    w4[j] = make_float4(e[0], e[1], e[2], e[3]);
  }
  if (tid < ROWS) {
    float b = 0.f;
    if (rowok) {
      b = bih[l * G4H + grow] + bhh[l * G4H + grow];
      if (l == 0) {   // fold Wih0 @ bl into the bias
        #pragma unroll
        for (int c = 0; c < CDIM; ++c) b = fmaf(wih0s[tid][c], bl[c], b);
      }
    }
    bias[tid] = b;
  }
  __syncthreads();

  // ---- wavefront tick loop: d = 6f + t
  long glimit = 1L << 20;
  for (int m = 0; m < NTICK; ++m) {
    const int fh0 = m / 6;
    const int f_hi = (fh0 > 95) ? 95 : fh0;
    const int f_lo = (m < 10) ? 0 : (m - 10) / 6;   // ceil((m-15)/6) clamped

    // ---- stage/spin: words w = tid, tid+256, tid+512 of 3*234
    const u64 *s0 = nullptr, *s1 = nullptr, *s2 = nullptr;
    u64 *d0 = nullptr, *d1 = nullptr, *d2 = nullptr;

    auto setup = [&](int w, const u64*& sp, u64*& dp) {
      const int k = w / NWORD;
      const int f = f_lo + k;
      if (f > f_hi) return;
      const int t = m - 6 * f;
      const int o = w - k * NWORD;
      if (o < 117) {                       // x-section word
        if (l == 0 && f == 0) {            // seed from X (12 floats, rest 0)
          vin[k][2 * o]     = (2 * o     < CDIM) ? xs[t][2 * o]     : 0.f;
          vin[k][2 * o + 1] = (2 * o + 1 < CDIM) ? xs[t][2 * o + 1] : 0.f;
          return;
        }
        sp = (l == 0)
           ? hu + ((size_t)5 * NSLOT + 16 * (f - 1) + t) * hps + o
           : hu + ((size_t)(l - 1) * NSLOT + 16 * f + t) * hps + o;
        dp = (u64*)&vin[k][2 * o];
      } else {                             // h-section word
        const int jj = o - 117;
        if (t == 0) {
          vin[k][HP + 2 * jj] = 0.f; vin[k][HP + 2 * jj + 1] = 0.f;
          return;
        }
        sp = hu + ((size_t)l * NSLOT + 16 * f + t - 1) * hps + jj;
        dp = (u64*)&vin[k][HP + 2 * jj];
      }
    };
    setup(tid, s0, d0);
    setup(tid + 256, s1, d1);
    if (tid + 512 < 3 * NWORD) setup(tid + 512, s2, d2);

    long gd = 0;
    while (s0 || s1 || s2) {
      if (s0) { u64 v = __hip_atomic_load(s0, __ATOMIC_RELAXED, AG); if (rdy(v)) { *d0 = v; s0 = nullptr; } }
      if (s1) { u64 v = __hip_atomic_load(s1, __ATOMIC_RELAXED, AG); if (rdy(v)) { *d1 = v; s1 = nullptr; } }
      if (s2) { u64 v = __hip_atomic_load(s2, __ATOMIC_RELAXED, AG); if (rdy(v)) { *d2 = v; s2 = nullptr; } }
      if (++gd > glimit) { glimit = 64; break; }   // bail loudly (NaNs), no hang
      if (gd > 8) __builtin_amdgcn_s_sleep(1);
    }
    __syncthreads();

    // ---- matvec: 3 streams, weights from regs, vin via LDS broadcast
    const float4* va = (const float4*)&vin[0][0];
    const float4* vb = (const float4*)&vin[1][0];
    const float4* vc = (const float4*)&vin[2][0];
    float a0 = 0.f, a1 = 0.f, a2 = 0.f;
    #pragma unroll
    for (int j = 0; j < 31; ++j) {
      const int c = q * 31 + j;
      const float4 wv = w4[j];
      const float4 y0 = va[c];
      a0 = fmaf(wv.x, y0.x, fmaf(wv.y, y0.y, fmaf(wv.z, y0.z, fmaf(wv.w, y0.w, a0))));
      const float4 y1 = vb[c];
      a1 = fmaf(wv.x, y1.x, fmaf(wv.y, y1.y, fmaf(wv.z, y1.z, fmaf(wv.w, y1.w, a1))));
      const float4 y2 = vc[c];
      a2 = fmaf(wv.x, y2.x, fmaf(wv.y, y2.y, fmaf(wv.z, y2.z, fmaf(wv.w, y2.w, a2))));
    }
    part[0][tid] = a0; part[1][tid] = a1; part[2][tid] = a2;
    __syncthreads();

    // ---- cell + publish (wave 0; rows of invalid units have zero weights)
    if (tid < 48) {
      const int k = tid >> 4, uu = tid & 15;
      const int f = f_lo + k;
      const bool act = (f <= f_hi);
      float hn = 0.f;
      int t = 0;
      if (act) {
        t = m - 6 * f;
        const int b3 = f % 3;
        float gg[4];
        #pragma unroll
        for (int g2 = 0; g2 < 4; ++g2) {
          const int rr = 4 * uu + g2;
          float s = part[k][rr] + part[k][rr + 64] + part[k][rr + 128] +
                    part[k][rr + 192] + bias[rr];
          if (l == 0 && f == 0) {          // f==0: x is the raw 12-dim seed
            #pragma unroll
            for (int c = 0; c < CDIM; ++c) s = fmaf(wih0s[rr][c], xs[t][c], s);
          }
          gg[g2] = s;
        }
        if (uu < U) {
          const float cp = (t == 0) ? 0.f : cst[b3][uu];
          const float cn = sigf(gg[1]) * cp + sigf(gg[0]) * tanhf(gg[2]);
          hn = sigf(gg[3]) * tanhf(cn);
          cst[b3][uu] = cn;
        }
      }
      const float hi = __shfl(hn, tid | 1);   // pair-pack (hn=0 beyond U)
      if (act && (uu & 1) == 0 && uu < U) {
        const u64 pv = ((u64)__float_as_uint(hi) << 32) | (u64)__float_as_uint(hn);
        __hip_atomic_store(hu + ((size_t)l * NSLOT + 16 * f + t) * hps + (j0 >> 1) + (uu >> 1),
                           pv, __ATOMIC_RELAXED, AG);
      }
    }
    // 2 barriers/tick; cell finishes before next tick's matvec barrier.
  }
}

extern "C" void kernel_launch(void* const* d_in, const int* in_sizes, int n_in,
                              void* d_out, int out_size, void* d_ws, size_t ws_size,
                              hipStream_t stream) {
  const float* X    = (const float*)d_in[0];
  const float* Wih0 = (const float*)d_in[1];
  const float* Wih  = (const float*)d_in[2];
  const float* Whh  = (const float*)d_in[3];
  const float* bih  = (const float*)d_in[4];
  const float* bhh  = (const float*)d_in[5];
  const float* Wl   = (const float*)d_in[6];
  const float* bl   = (const float*)d_in[7];

  // workspace: hout[6][1536][hp] f32 only (weights folded per-WG, no W0' buffer)
  size_t need240 = (size_t)NL * NSLOT * 240 * 4;
  const int hp = (ws_size >= need240) ? 240 : 234;
  float* hout = (float*)d_ws;

  init_kernel<<<2048, 256, 0, stream>>>((unsigned*)hout, hp);
  lstm_pipe<<<NL * GPL + NHEAD, BLOCK, 0, stream>>>(
      X, Wih0, Wih, Whh, bih, bhh, Wl, bl, (float*)d_out, hout, hp / 2);
}